// Round 6
// baseline (1368.942 us; speedup 1.0000x reference)
//
#include <hip/hip_runtime.h>
#include <stdint.h>

// VQ-VAE codebook argmin, f32 in / f32 out.
// R6: barrier-free k_argmin — MFMA fragments loaded directly global->VGPR
// (coalesced 16B/lane), no LDS in main loop; branchless packed top-2;
// pruned exact numpy-f32 re-rank; fused prep; atomic loss.

#define B_ROWS 32768
#define DIM    512
#define KCODES 8192
#define SUPERS 2
#define TILES  32          // per super: 32 tiles * 128 = 4096 codes
#define PRUNE_MARGIN 3e-4f // > f32-bin(6.1e-5) + 2*bf16 dot err(5e-5) + pack(8e-6)

typedef short bhalf8_t __attribute__((ext_vector_type(8)));
typedef float f32x4_t  __attribute__((ext_vector_type(4)));

__device__ __forceinline__ float b2f(unsigned short u) {
    return __uint_as_float(((unsigned int)u) << 16);
}
__device__ __forceinline__ unsigned short f2b(float f) {  // RNE
    unsigned int x = __float_as_uint(f);
    return (unsigned short)((x + 0x7FFFu + ((x >> 16) & 1u)) >> 16);
}

// ---------- K0: fused f32->bf16 convert + numpy-pairwise row sumsq ----------
__global__ __launch_bounds__(256) void k_prep(const float* __restrict__ X,
                                              unsigned short* __restrict__ Xh,
                                              float* __restrict__ sq, int nrows,
                                              float* __restrict__ lossInit) {
    if (lossInit && blockIdx.x == 0 && threadIdx.x == 0) *lossInit = 0.f;
    int wid = threadIdx.x >> 6, lane = threadIdx.x & 63;
    int r = blockIdx.x * 4 + wid;
    if (r >= nrows) return;
    // bf16 convert, coalesced 32B-in / 16B-out per lane
    float4 a = *(const float4*)(X + (size_t)r * DIM + lane * 8);
    float4 b = *(const float4*)(X + (size_t)r * DIM + lane * 8 + 4);
    uint4 o;
    o.x = (unsigned)f2b(a.x) | ((unsigned)f2b(a.y) << 16);
    o.y = (unsigned)f2b(a.z) | ((unsigned)f2b(a.w) << 16);
    o.z = (unsigned)f2b(b.x) | ((unsigned)f2b(b.y) << 16);
    o.w = (unsigned)f2b(b.z) | ((unsigned)f2b(b.w) << 16);
    *(uint4*)(Xh + (size_t)r * DIM + lane * 8) = o;
    // numpy pairwise sumsq (R4/R5-proven exact emulation); re-reads are L1 hits
    int bb = lane >> 3, j = lane & 7;
    float acc = 0.f;
    if (bb < 4) {
        const float* x = X + (size_t)r * DIM + bb * 128 + j;
        float v = x[0];
        acc = __fmul_rn(v, v);
        for (int i = 1; i < 16; i++) {
            float w = x[8 * i];
            acc = __fadd_rn(acc, __fmul_rn(w, w));
        }
    }
    float t = __fadd_rn(acc, __shfl_xor(acc, 1));
    t = __fadd_rn(t, __shfl_xor(t, 2));
    t = __fadd_rn(t, __shfl_xor(t, 4));
    float u = __fadd_rn(t, __shfl_xor(t, 8));
    u = __fadd_rn(u, __shfl_xor(u, 16));
    if (lane == 0) sq[r] = u;
}

// ---------- K1: barrier-free bf16 MFMA GEMM + packed top-2 -> top-8/super ----------
// 512 blocks; super = b&1 matches XCD round-robin (b%8) => one 4MB W-half per XCD L2.
__global__ __launch_bounds__(256, 2) void k_argmin(const unsigned short* __restrict__ Zh,
                                                   const unsigned short* __restrict__ Wh,
                                                   const float* __restrict__ ww,
                                                   float2* __restrict__ part) {
    __shared__ alignas(16) uint32_t keys[128 * 64];   // 32KB, used only in reduce tail
    const int tid = threadIdx.x;
    const int lane = tid & 63, w = tid >> 6;
    const int wm = w >> 1, wn = w & 1;
    const int lane15 = lane & 15, q = lane >> 4;
    const int b = blockIdx.x;
    const int super = b & 1;
    const int rb = (b >> 1) * 128;

    // fragment base pointers: lane-exact, K-offset becomes compile-time imm
    const char* pA[4];
    const char* pB[4];
#pragma unroll
    for (int f = 0; f < 4; f++) {
        pA[f] = (const char*)(Zh + (size_t)(rb + wm * 64 + f * 16 + lane15) * DIM + q * 8);
        pB[f] = (const char*)(Wh + (size_t)(super * 4096 + wn * 64 + f * 16 + lane15) * DIM + q * 8);
    }

    uint32_t p1[4][4], p2[4][4];
#pragma unroll
    for (int i = 0; i < 4; i++)
#pragma unroll
        for (int jj = 0; jj < 4; jj++) { p1[i][jj] = 0xFFFFFFFFu; p2[i][jj] = 0xFFFFFFFFu; }

    for (int tl = 0; tl < TILES; ++tl) {
        const int nt = super * 4096 + tl * 128;
        f32x4_t acc[4][4];
#pragma unroll
        for (int i = 0; i < 4; i++)
#pragma unroll
            for (int jj = 0; jj < 4; jj++) acc[i][jj] = (f32x4_t){0.f, 0.f, 0.f, 0.f};

#pragma unroll
        for (int ks = 0; ks < 16; ks++) {        // BK=32 per step, byte offset ks*64
            bhalf8_t af[4], bf[4];
#pragma unroll
            for (int f = 0; f < 4; f++) {
                af[f] = *(const bhalf8_t*)(pA[f] + ks * 64);
                bf[f] = *(const bhalf8_t*)(pB[f] + ks * 64);
            }
#pragma unroll
            for (int fm = 0; fm < 4; fm++)
#pragma unroll
                for (int fn = 0; fn < 4; fn++)
                    acc[fm][fn] = __builtin_amdgcn_mfma_f32_16x16x32_bf16(af[fm], bf[fn], acc[fm][fn], 0, 0, 0);
        }
#pragma unroll
        for (int f = 0; f < 4; f++) pB[f] += 128 * DIM * 2;   // next n-tile

        // epilogue: s' = (ww[n]+0.5) - 2*dot, pack hi-25 bits | 7-bit id, branchless top-2
        float cb[4];
#pragma unroll
        for (int fn = 0; fn < 4; fn++)
            cb[fn] = ww[nt + wn * 64 + fn * 16 + lane15] + 0.5f;
#pragma unroll
        for (int fm = 0; fm < 4; fm++)
#pragma unroll
            for (int r = 0; r < 4; r++)
#pragma unroll
                for (int fn = 0; fn < 4; fn++) {
                    float sv = fmaf(-2.0f, acc[fm][fn][r], cb[fn]);
                    uint32_t pk = (__float_as_uint(sv) & 0xFFFFFF80u) | (uint32_t)(tl * 4 + fn);
                    uint32_t mx = max(p1[fm][r], pk);
                    p1[fm][r] = min(p1[fm][r], pk);
                    p2[fm][r] = min(p2[fm][r], mx);
                }
    }

    // per-row top-8 of 64 packed keys via LDS
    __syncthreads();
#pragma unroll
    for (int fm = 0; fm < 4; fm++)
#pragma unroll
        for (int r = 0; r < 4; r++) {
            int row = wm * 64 + fm * 16 + q * 4 + r;   // C/D row = (lane>>4)*4 + reg
            int slice = wn * 16 + lane15;
            keys[(row * 32 + slice) * 2 + 0] = p1[fm][r];
            keys[(row * 32 + slice) * 2 + 1] = p2[fm][r];
        }
    __syncthreads();
    if (tid < 128) {
        int row = tid;
        int rglob = rb + row;
        for (int s = 0; s < 8; s++) {
            uint32_t bk = 0xFFFFFFFFu; int be = 0;
            for (int e = 0; e < 64; e++) {
                uint32_t k = keys[row * 64 + e];
                if (k < bk) { bk = k; be = e; }
            }
            int slice = be >> 1;
            int id = (int)(bk & 127u);
            int n = super * 4096 + (id >> 2) * 128 + (slice >> 4) * 64 + (id & 3) * 16 + (slice & 15);
            part[((size_t)rglob * SUPERS + super) * 8 + s] =
                make_float2(__uint_as_float(bk), __int_as_float(n));
            keys[row * 64 + be] = 0xFFFFFFFFu;  // consume
        }
    }
}

// ---------- K2: pruned exact numpy-f32 re-rank of 16 candidates ----------
__global__ __launch_bounds__(256) void k_exact(const float* __restrict__ Zf,
                                               const float* __restrict__ Wf,
                                               const float2* __restrict__ part,
                                               const float* __restrict__ zz,
                                               const float* __restrict__ ww,
                                               float* __restrict__ outf,
                                               float* __restrict__ lossAcc) {
    int wid = threadIdx.x >> 6, lane = threadIdx.x & 63;
    int r = blockIdx.x * 4 + wid;
    int c = lane >> 2, j = lane & 3;   // candidate 0..15, SSE lane 0..3

    float2 P = part[((size_t)r * SUPERS + (c >> 3)) * 8 + (c & 7)];
    int n = __float_as_int(P.y);
    n = min(max(n, 0), KCODES - 1);
    uint32_t ku = __float_as_uint(P.x) & 0xFFFFFF80u;

    // prune: only candidates whose key is within margin of the wave-min key
    uint32_t kmin = ku;
#pragma unroll
    for (int off = 32; off; off >>= 1) kmin = min(kmin, (uint32_t)__shfl_xor((int)kmin, off));
    bool active = __uint_as_float(ku) <= __uint_as_float(kmin) + PRUNE_MARGIN;

    // numpy einsum baseline-SIMD: 4 stride-4 f32 accumulators (mul+add, no FMA)
    float acc = 0.f;
    if (active) {
        const float* zp = Zf + (size_t)r * DIM + j;
        const float* wp = Wf + (size_t)n * DIM + j;
        for (int i = 0; i < 128; i++)
            acc = __fadd_rn(acc, __fmul_rn(zp[4 * i], wp[4 * i]));
    }
    float t = __fadd_rn(acc, __shfl_xor(acc, 1));
    t = __fadd_rn(t, __shfl_xor(t, 2));
    float dot = __shfl(t, c * 4);

    float t1 = __fadd_rn(zz[r], ww[n]);
    float t2 = __fmul_rn(2.0f, dot);
    float d2 = __fadd_rn(t1, -t2);

    float bd = (j == 0 && active) ? d2 : 3.4e38f;
    int   bn = (j == 0 && active) ? n  : 0x7FFFFFFF;
#pragma unroll
    for (int off = 32; off; off >>= 1) {
        float od = __shfl_xor(bd, off);
        int   on = __shfl_xor(bn, off);
        if (od < bd || (od == bd && on < bn)) { bd = od; bn = on; }
    }
    int idx = bn;

    // outputs: z_q exact f32 copy, index, loss partial (atomic, pre-scaled)
    float4 wa = *(const float4*)(Wf + (size_t)idx * DIM + lane * 8);
    float4 wb = *(const float4*)(Wf + (size_t)idx * DIM + lane * 8 + 4);
    float4 za = *(const float4*)(Zf + (size_t)r   * DIM + lane * 8);
    float4 zb = *(const float4*)(Zf + (size_t)r   * DIM + lane * 8 + 4);
    *(float4*)(outf + (size_t)r * DIM + lane * 8)     = wa;
    *(float4*)(outf + (size_t)r * DIM + lane * 8 + 4) = wb;
    float d0 = za.x - wa.x, d1 = za.y - wa.y, dd2 = za.z - wa.z, d3 = za.w - wa.w;
    float d4 = zb.x - wb.x, d5 = zb.y - wb.y, d6 = zb.z - wb.z, d7 = zb.w - wb.w;
    float ls = d0*d0 + d1*d1 + dd2*dd2 + d3*d3 + d4*d4 + d5*d5 + d6*d6 + d7*d7;
#pragma unroll
    for (int off = 32; off; off >>= 1) ls += __shfl_xor(ls, off);
    if (lane == 0) {
        outf[(size_t)B_ROWS * DIM + r] = (float)idx;
        atomicAdd(lossAcc, ls * (1.25f / 16777216.0f));
    }
}

extern "C" void kernel_launch(void* const* d_in, const int* in_sizes, int n_in,
                              void* d_out, int out_size, void* d_ws, size_t ws_size,
                              hipStream_t stream) {
    (void)in_sizes; (void)n_in; (void)out_size; (void)ws_size;
    const float* Zf = (const float*)d_in[0];   // [32768, 512] f32
    const float* Wf = (const float*)d_in[1];   // [8192, 512]  f32
    float* outf = (float*)d_out;               // f32: z_q | indices | loss

    // bf16 scratch inside d_out's z_q region (64 MB): Zh 32MB @0 | Wh 8MB @32MB.
    // k_exact overwrites it with the final z_q (k_argmin completed by then).
    unsigned short* Zh = (unsigned short*)d_out;
    unsigned short* Wh = (unsigned short*)((char*)d_out + (32ull << 20));
    float* lossAcc = outf + (size_t)B_ROWS * DIM + B_ROWS;

    // ws (4.39 MB, proven): ww 32KB @0 | zz 128KB @32K | part 4MB @192K
    float*  ww    = (float*)d_ws;
    float*  zz    = (float*)((char*)d_ws + 32768);
    float2* partp = (float2*)((char*)d_ws + 196608);

    k_prep<<<KCODES / 4, 256, 0, stream>>>(Wf, Wh, ww, KCODES, lossAcc);
    k_prep<<<B_ROWS / 4, 256, 0, stream>>>(Zf, Zh, zz, B_ROWS, nullptr);
    k_argmin<<<(B_ROWS / 128) * SUPERS, 256, 0, stream>>>(Zh, Wh, ww, partp);
    k_exact<<<B_ROWS / 4, 256, 0, stream>>>(Zf, Wf, partp, zz, ww, outf, lossAcc);
}